// Round 1
// 418.528 us; speedup vs baseline: 1.0247x; 1.0247x over previous
//
#include <hip/hip_runtime.h>

// Problem constants (fixed by setup_inputs) — ALL TENSORS ARE FLOAT32.
#define B 4
#define H 16
#define S 2048
#define D 64
#define M 1000
#define TOPKN 10
#define HID 1024   // H*D

// Flat output element offsets (f32 elements)
//  out0 inputs  [4,2048,1024]   @ 0
//  out1 q       [4,16,2048,64]  @ 8388608
//  out2 k_aug   [4,16,2058,64]  @ 16777216
//  out3 v_aug   [4,16,2058,64]  @ 25206784
//  out4 mask_aug[4,2058]        @ 33636352
//  out5 seq_len_k scalar        @ 33644584
//  out6 positions_k [4,2058]    @ 33644585   (total 33652817 elems)
#define O4E 33636352U
#define O5E 33644584U
#define O6E 33644585U
// float4-chunk constants (4 f32 = 16 B per chunk)
#define O2C 4194304U   // out2 offset in chunks
#define O3C 6301696U   // out3 offset in chunks
#define BHSTR 32928U   // 2058*64/4 chunks per (b,h) in k_aug/v_aug
#define CF 2097152U    // 8,388,608 elems / 4 per flat region
#define T4C (4u * CF)  // total copy chunks = 8,388,608

// Persistent-grid sizing: 2048 blocks = 256 CU x 8 blocks/CU (wave-limit
// capacity at 256 thr/blk).  Blocks 0..3 = special per-batch blocks,
// blocks 4..2047 = grid-stride copy.  All co-resident from t=0.
#define NCOPYBLK 2044
#define NTH (NCOPYBLK * 256u)  // copy-thread count = 523,264

__device__ __forceinline__ void chunk_src_dst(
    unsigned int c, const float4* __restrict__ s0,
    const float4* __restrict__ s1, const float4* __restrict__ s2,
    const float4* __restrict__ s3, float4& val, unsigned int& dst) {
  if (c < CF) {
    val = s0[c];
    dst = c;
  } else if (c < 2u * CF) {
    val = s1[c - CF];
    dst = c;
  } else {
    bool isv = (c >= 3u * CF);
    unsigned int idx = c - (isv ? 3u : 2u) * CF;
    unsigned int bh = idx >> 15;  // 2048*64/4 = 32768 chunks per (b,h)
    unsigned int r = idx & 32767u;
    dst = (isv ? O3C : O2C) + bh * BHSTR + 160u + r;  // skip 10 retrieved rows
    val = (isv ? s3 : s2)[idx];
  }
}

__global__ __launch_bounds__(256) void fused_kernel(
    const float* __restrict__ in0, const float* __restrict__ qin,
    const float* __restrict__ kin, const float* __restrict__ vin,
    const float* __restrict__ amask, const float* __restrict__ mkeys,
    const float* __restrict__ mvals, const float* __restrict__ mpos,
    float* __restrict__ out, unsigned int outElems) {
  const int blk = blockIdx.x;
  const int tid = threadIdx.x;
  const unsigned int outChunks = outElems >> 2;

  __shared__ float4 s_q4[256];    // query vector, float4-packed
  __shared__ float s_sims[1024];  // sims padded with -inf
  __shared__ float s_rv[256];
  __shared__ int s_ri[256];
  __shared__ int s_top[TOPKN];
  __shared__ float s_qn;

  if (blk >= B) {
    // ---- persistent grid-stride bulk copy: 16 chunks/thread + tail ----
    const float4* s0 = (const float4*)in0;
    const float4* s1 = (const float4*)qin;
    const float4* s2 = (const float4*)kin;
    const float4* s3 = (const float4*)vin;
    float4* o = (float4*)out;
    unsigned int c = (unsigned int)(blk - B) * 256u + (unsigned int)tid;
    // main loop: 4 independent loads in flight before the 4 stores (MLP)
    while (c + 3u * NTH < T4C) {
      float4 v0, v1, v2, v3;
      unsigned int d0, d1, d2, d3;
      chunk_src_dst(c, s0, s1, s2, s3, v0, d0);
      chunk_src_dst(c + NTH, s0, s1, s2, s3, v1, d1);
      chunk_src_dst(c + 2u * NTH, s0, s1, s2, s3, v2, d2);
      chunk_src_dst(c + 3u * NTH, s0, s1, s2, s3, v3, d3);
      if (d0 < outChunks) o[d0] = v0;
      if (d1 < outChunks) o[d1] = v1;
      if (d2 < outChunks) o[d2] = v2;
      if (d3 < outChunks) o[d3] = v3;
      c += 4u * NTH;
    }
    for (; c < T4C; c += NTH) {  // at most 1 iteration (t < 16384)
      float4 v;
      unsigned int d;
      chunk_src_dst(c, s0, s1, s2, s3, v, d);
      if (d < outChunks) o[d] = v;
    }
  } else {
    // ---- special block: one per batch (blocks 0..3, dispatched first) ----
    const int b = blk;
    const int SK = S + TOPKN;  // 2058

    // mask_aug = [ones(K), mask]; positions_k[0:S] = arange(S)
    for (int i = tid; i < SK; i += 256) {
      unsigned int d4 = O4E + (unsigned int)(b * SK + i);
      if (d4 < outElems)
        out[d4] = (i < TOPKN) ? 1.0f : amask[b * S + (i - TOPKN)];
      unsigned int d6 = O6E + (unsigned int)(b * SK + i);
      if (i < S && d6 < outElems) out[d6] = (float)i;
    }
    if (b == 0 && tid == 0 && O5E < outElems)
      out[O5E] = 2064.0f;  // ref value is bf16-rounded 2058 (proven round 0)

    // load query as float4: query_key[h*64+d] = k[b, h, S-1, d]
    {
      int h = tid >> 4;             // 16 float4 per head row
      int dd = (tid & 15) << 2;     // element offset within head, 16B-aligned
      s_q4[tid] = *(const float4*)(kin + (((size_t)(b * H + h) * S + (S - 1)) *
                                              D +
                                          dd));
    }
    __syncthreads();

    // query norm via LDS tree reduction
    {
      float4 qv = s_q4[tid];
      s_rv[tid] = qv.x * qv.x + qv.y * qv.y + qv.z * qv.z + qv.w * qv.w;
      __syncthreads();
      for (int w = 128; w > 0; w >>= 1) {
        if (tid < w) s_rv[tid] += s_rv[tid + w];
        __syncthreads();
      }
      if (tid == 0) s_qn = sqrtf(s_rv[0]) + 1e-8f;
      __syncthreads();
    }

    // sims[m] = dot(q, mem[m]) / ((|q|+eps)*(|mem[m]|+eps)); 4 rows/thread.
    // s_q4[jj] is a uniform-address LDS read -> broadcast, conflict-free.
    const float4* mk4 = (const float4*)mkeys;
    for (int m = tid; m < 1024; m += 256) {
      if (m < M) {
        float dot = 0.f, msq = 0.f;
#pragma unroll 4
        for (int jj = 0; jj < 256; ++jj) {  // 1024 f32 = 256 float4/row
          float4 ch = mk4[(size_t)m * 256 + jj];
          float4 qq = s_q4[jj];
          dot += qq.x * ch.x + qq.y * ch.y + qq.z * ch.z + qq.w * ch.w;
          msq += ch.x * ch.x + ch.y * ch.y + ch.z * ch.z + ch.w * ch.w;
        }
        s_sims[m] = dot / (s_qn * (sqrtf(msq) + 1e-8f));
      } else {
        s_sims[m] = -INFINITY;
      }
    }
    __syncthreads();

    // top-10: LDS-tree argmax x10 (ties -> lowest index, JAX semantics).
    // bi always a valid in-range index — NaN-proof, no sentinel can escape.
    for (int t = 0; t < TOPKN; ++t) {
      int base = tid * 4;
      float bv = s_sims[base];
      int bi = base;
      for (int j = 1; j < 4; ++j) {
        float v = s_sims[base + j];
        if (v > bv) { bv = v; bi = base + j; }  // '>' keeps lowest index
      }
      s_rv[tid] = bv;
      s_ri[tid] = bi;
      __syncthreads();
      for (int w = 128; w > 0; w >>= 1) {
        if (tid < w) {
          float ov = s_rv[tid + w];
          int oi = s_ri[tid + w];
          if (ov > s_rv[tid] || (ov == s_rv[tid] && oi < s_ri[tid])) {
            s_rv[tid] = ov;
            s_ri[tid] = oi;
          }
        }
        __syncthreads();
      }
      if (tid == 0) {
        int sel = s_ri[0];                     // in [0,1024) by construction
        s_sims[sel] = -INFINITY;
        s_top[t] = (sel < M) ? sel : (M - 1);  // clamp for gather safety
      }
      __syncthreads();
    }

    // r_pos tail of positions_k
    if (tid < TOPKN) {
      unsigned int d6 = O6E + (unsigned int)(b * SK + S + tid);
      if (d6 < outElems) out[d6] = mpos[s_top[tid]];
    }

    // gather retrieved rows: k_aug/v_aug[b,h,kk,:] = mem[im][h*64 .. h*64+63]
    // 2 * H * TOPK * 16 chunks = 5120 chunks per batch.
    const float4* mv4 = (const float4*)mvals;
    float4* o = (float4*)out;
    for (int c = tid; c < 5120; c += 256) {
      int isv = (c >= 2560);
      int cc = isv ? c - 2560 : c;
      int row = cc >> 4, ch = cc & 15;  // 16 chunks per 64-elem row
      int h = row / 10, kk = row - h * 10;
      int im = s_top[kk];               // clamped to [0, M)
      const float4* src = isv ? mv4 : mk4;
      unsigned int dst = (isv ? O3C : O2C) +
                         (unsigned int)((b * H + h) * BHSTR + kk * 16 + ch);
      if (dst < outChunks) o[dst] = src[(size_t)im * 256 + h * 16 + ch];
    }
  }
}

// ---------------------------------------------------------------------------
extern "C" void kernel_launch(void* const* d_in, const int* in_sizes, int n_in,
                              void* d_out, int out_size, void* d_ws, size_t ws_size,
                              hipStream_t stream) {
  const float* in0 = (const float*)d_in[0];  // inputs  [4,2048,1024]
  const float* q   = (const float*)d_in[1];  // q       [4,16,2048,64]
  const float* k   = (const float*)d_in[2];  // k
  const float* v   = (const float*)d_in[3];  // v
  const float* am  = (const float*)d_in[4];  // attention_mask [4,2048]
  const float* mk  = (const float*)d_in[5];  // mem_keys   [1000,1024]
  const float* mv  = (const float*)d_in[6];  // mem_values [1000,1024]
  const float* mp  = (const float*)d_in[7];  // mem_positions [1000]
  // d_in[8] = seq_len_q (unused; S fixed at 2048)
  (void)in_sizes; (void)n_in; (void)d_ws; (void)ws_size;

  fused_kernel<<<B + NCOPYBLK, 256, 0, stream>>>(
      in0, q, k, v, am, mk, mv, mp, (float*)d_out, (unsigned int)out_size);
}

// Round 2
// 284.230 us; speedup vs baseline: 1.5089x; 1.4725x over previous
//
#include <hip/hip_runtime.h>

// Problem constants (fixed by setup_inputs) — ALL TENSORS ARE FLOAT32.
#define B 4
#define H 16
#define S 2048
#define D 64
#define M 1000
#define TOPKN 10
#define HID 1024   // H*D

// Flat output element offsets (f32 elements)
//  out0 inputs  [4,2048,1024]   @ 0
//  out1 q       [4,16,2048,64]  @ 8388608
//  out2 k_aug   [4,16,2058,64]  @ 16777216
//  out3 v_aug   [4,16,2058,64]  @ 25206784
//  out4 mask_aug[4,2058]        @ 33636352
//  out5 seq_len_k scalar        @ 33644584
//  out6 positions_k [4,2058]    @ 33644585   (total 33652817 elems)
#define O4E 33636352U
#define O5E 33644584U
#define O6E 33644585U
// float4-chunk constants (4 f32 = 16 B per chunk)
#define O2C 4194304U   // out2 offset in chunks
#define O3C 6301696U   // out3 offset in chunks
#define BHSTR 32928U   // 2058*64/4 chunks per (b,h) in k_aug/v_aug
#define CF 2097152U    // 8,388,608 elems / 4 per flat region
#define T4C (4u * CF)  // total copy chunks = 8,388,608

// Stage-1 grid: 125 sims blocks (8 rows each = M exactly) + 1923 copy blocks
// = 2048 blocks = 256 CU x 8 blocks/CU wave-limit capacity, all co-resident.
#define NSIMS 125
#define NCOPYBLK 1923
#define NTH (NCOPYBLK * 256u)  // copy-thread count = 492,288

__device__ __forceinline__ void chunk_src_dst(
    unsigned int c, const float4* __restrict__ s0,
    const float4* __restrict__ s1, const float4* __restrict__ s2,
    const float4* __restrict__ s3, float4& val, unsigned int& dst) {
  if (c < CF) {
    val = s0[c];
    dst = c;
  } else if (c < 2u * CF) {
    val = s1[c - CF];
    dst = c;
  } else {
    bool isv = (c >= 3u * CF);
    unsigned int idx = c - (isv ? 3u : 2u) * CF;
    unsigned int bh = idx >> 15;  // 2048*64/4 = 32768 chunks per (b,h)
    unsigned int r = idx & 32767u;
    dst = (isv ? O3C : O2C) + bh * BHSTR + 160u + r;  // skip 10 retrieved rows
    val = (isv ? s3 : s2)[idx];
  }
}

// ---------------------------------------------------------------------------
// Stage 1: bulk copy (persistent grid-stride) + sims[b][m] -> ws.
// sims blocks: one WAVE per memory row, coalesced row reads, shuffle reduce.
__global__ __launch_bounds__(256) void fused_stage1(
    const float* __restrict__ in0, const float* __restrict__ qin,
    const float* __restrict__ kin, const float* __restrict__ vin,
    const float* __restrict__ mkeys, float* __restrict__ out,
    float* __restrict__ ws, unsigned int outElems) {
  const int blk = blockIdx.x;
  const int tid = threadIdx.x;

  __shared__ float4 s_q4[B][256];  // 4 query vectors, float4-packed (16 KB)
  __shared__ float s_qn[B];

  if (blk >= NSIMS) {
    // ---- persistent grid-stride bulk copy ----
    const unsigned int outChunks = outElems >> 2;
    const float4* s0 = (const float4*)in0;
    const float4* s1 = (const float4*)qin;
    const float4* s2 = (const float4*)kin;
    const float4* s3 = (const float4*)vin;
    float4* o = (float4*)out;
    unsigned int c = (unsigned int)(blk - NSIMS) * 256u + (unsigned int)tid;
    // main loop: 4 independent loads in flight before the 4 stores (MLP)
    while (c + 3u * NTH < T4C) {
      float4 v0, v1, v2, v3;
      unsigned int d0, d1, d2, d3;
      chunk_src_dst(c, s0, s1, s2, s3, v0, d0);
      chunk_src_dst(c + NTH, s0, s1, s2, s3, v1, d1);
      chunk_src_dst(c + 2u * NTH, s0, s1, s2, s3, v2, d2);
      chunk_src_dst(c + 3u * NTH, s0, s1, s2, s3, v3, d3);
      if (d0 < outChunks) o[d0] = v0;
      if (d1 < outChunks) o[d1] = v1;
      if (d2 < outChunks) o[d2] = v2;
      if (d3 < outChunks) o[d3] = v3;
      c += 4u * NTH;
    }
    for (; c < T4C; c += NTH) {
      float4 v;
      unsigned int d;
      chunk_src_dst(c, s0, s1, s2, s3, v, d);
      if (d < outChunks) o[d] = v;
    }
  } else {
    // ---- sims block: rows m = blk*8 .. blk*8+7 (125*8 = 1000 = M) ----
    // Load all 4 query vectors: query_key[b][h*64+d] = k[b, h, S-1, d].
    for (int i = tid; i < B * 256; i += 256) {
      int b = i >> 8, c = i & 255;
      int h = c >> 4, dd = (c & 15) << 2;
      s_q4[b][c] = *(const float4*)(kin +
                                    ((size_t)(b * H + h) * S + (S - 1)) * D +
                                    dd);
    }
    __syncthreads();

    const int lane = tid & 63;
    const int w = tid >> 6;  // wave id 0..3

    // q norms: wave w reduces batch w
    {
      float ss = 0.f;
      for (int j = 0; j < 4; ++j) {
        float4 v = s_q4[w][lane + j * 64];
        ss += v.x * v.x + v.y * v.y + v.z * v.z + v.w * v.w;
      }
      for (int off = 32; off; off >>= 1) ss += __shfl_xor(ss, off);
      if (lane == 0) s_qn[w] = sqrtf(ss) + 1e-8f;
    }
    __syncthreads();

    // Each wave: 2 rows; lanes read the 4 KB row coalesced (64x16B chunks).
    const float4* mk4 = (const float4*)mkeys;
    for (int r = 0; r < 2; ++r) {
      const int m = blk * 8 + w * 2 + r;  // always < M
      float d0 = 0.f, d1 = 0.f, d2 = 0.f, d3 = 0.f, msq = 0.f;
#pragma unroll
      for (int j = 0; j < 4; ++j) {
        float4 ch = mk4[(size_t)m * 256 + lane + j * 64];
        float4 q0 = s_q4[0][lane + j * 64];
        float4 q1 = s_q4[1][lane + j * 64];
        float4 q2 = s_q4[2][lane + j * 64];
        float4 q3 = s_q4[3][lane + j * 64];
        d0 += q0.x * ch.x + q0.y * ch.y + q0.z * ch.z + q0.w * ch.w;
        d1 += q1.x * ch.x + q1.y * ch.y + q1.z * ch.z + q1.w * ch.w;
        d2 += q2.x * ch.x + q2.y * ch.y + q2.z * ch.z + q2.w * ch.w;
        d3 += q3.x * ch.x + q3.y * ch.y + q3.z * ch.z + q3.w * ch.w;
        msq += ch.x * ch.x + ch.y * ch.y + ch.z * ch.z + ch.w * ch.w;
      }
      for (int off = 32; off; off >>= 1) {
        d0 += __shfl_xor(d0, off);
        d1 += __shfl_xor(d1, off);
        d2 += __shfl_xor(d2, off);
        d3 += __shfl_xor(d3, off);
        msq += __shfl_xor(msq, off);
      }
      if (lane == 0) {
        float den = sqrtf(msq) + 1e-8f;  // same formula as proven kernel
        ws[0 * 1024 + m] = d0 / (s_qn[0] * den);
        ws[1 * 1024 + m] = d1 / (s_qn[1] * den);
        ws[2 * 1024 + m] = d2 / (s_qn[2] * den);
        ws[3 * 1024 + m] = d3 / (s_qn[3] * den);
      }
    }
  }
}

// ---------------------------------------------------------------------------
// Stage 2: per-batch top-10 from ws + mask/positions/seq_len + gather.
__global__ __launch_bounds__(256) void fused_stage2(
    const float* __restrict__ amask, const float* __restrict__ mkeys,
    const float* __restrict__ mvals, const float* __restrict__ mpos,
    const float* __restrict__ ws, float* __restrict__ out,
    unsigned int outElems) {
  const int b = blockIdx.x;
  const int tid = threadIdx.x;
  const unsigned int outChunks = outElems >> 2;
  const int SK = S + TOPKN;  // 2058

  __shared__ float s_sims[1024];  // sims padded with -inf
  __shared__ float s_rv[256];
  __shared__ int s_ri[256];
  __shared__ int s_top[TOPKN];

  for (int i = tid; i < 1024; i += 256)
    s_sims[i] = (i < M) ? ws[b * 1024 + i] : -INFINITY;

  // mask_aug = [ones(K), mask]; positions_k[0:S] = arange(S)
  for (int i = tid; i < SK; i += 256) {
    unsigned int d4 = O4E + (unsigned int)(b * SK + i);
    if (d4 < outElems)
      out[d4] = (i < TOPKN) ? 1.0f : amask[b * S + (i - TOPKN)];
    unsigned int d6 = O6E + (unsigned int)(b * SK + i);
    if (i < S && d6 < outElems) out[d6] = (float)i;
  }
  if (b == 0 && tid == 0 && O5E < outElems)
    out[O5E] = 2064.0f;  // ref value is bf16-rounded 2058 (proven round 0)
  __syncthreads();

  // top-10: LDS-tree argmax x10 (ties -> lowest index, JAX semantics).
  // bi always a valid in-range index — NaN-proof, no sentinel can escape.
  for (int t = 0; t < TOPKN; ++t) {
    int base = tid * 4;
    float bv = s_sims[base];
    int bi = base;
    for (int j = 1; j < 4; ++j) {
      float v = s_sims[base + j];
      if (v > bv) { bv = v; bi = base + j; }  // '>' keeps lowest index
    }
    s_rv[tid] = bv;
    s_ri[tid] = bi;
    __syncthreads();
    for (int w = 128; w > 0; w >>= 1) {
      if (tid < w) {
        float ov = s_rv[tid + w];
        int oi = s_ri[tid + w];
        if (ov > s_rv[tid] || (ov == s_rv[tid] && oi < s_ri[tid])) {
          s_rv[tid] = ov;
          s_ri[tid] = oi;
        }
      }
      __syncthreads();
    }
    if (tid == 0) {
      int sel = s_ri[0];                     // in [0,1024) by construction
      s_sims[sel] = -INFINITY;
      s_top[t] = (sel < M) ? sel : (M - 1);  // clamp for gather safety
    }
    __syncthreads();
  }

  // r_pos tail of positions_k
  if (tid < TOPKN) {
    unsigned int d6 = O6E + (unsigned int)(b * SK + S + tid);
    if (d6 < outElems) out[d6] = mpos[s_top[tid]];
  }

  // gather retrieved rows: k_aug/v_aug[b,h,kk,:] = mem[im][h*64 .. h*64+63]
  // 2 * H * TOPK * 16 chunks = 5120 chunks per batch.
  const float4* mk4 = (const float4*)mkeys;
  const float4* mv4 = (const float4*)mvals;
  float4* o = (float4*)out;
  for (int c = tid; c < 5120; c += 256) {
    int isv = (c >= 2560);
    int cc = isv ? c - 2560 : c;
    int row = cc >> 4, ch = cc & 15;  // 16 chunks per 64-elem row
    int h = row / 10, kk = row - h * 10;
    int im = s_top[kk];               // clamped to [0, M)
    const float4* src = isv ? mv4 : mk4;
    unsigned int dst = (isv ? O3C : O2C) +
                       (unsigned int)((b * H + h) * BHSTR + kk * 16 + ch);
    if (dst < outChunks) o[dst] = src[(size_t)im * 256 + h * 16 + ch];
  }
}

// ---------------------------------------------------------------------------
extern "C" void kernel_launch(void* const* d_in, const int* in_sizes, int n_in,
                              void* d_out, int out_size, void* d_ws, size_t ws_size,
                              hipStream_t stream) {
  const float* in0 = (const float*)d_in[0];  // inputs  [4,2048,1024]
  const float* q   = (const float*)d_in[1];  // q       [4,16,2048,64]
  const float* k   = (const float*)d_in[2];  // k
  const float* v   = (const float*)d_in[3];  // v
  const float* am  = (const float*)d_in[4];  // attention_mask [4,2048]
  const float* mk  = (const float*)d_in[5];  // mem_keys   [1000,1024]
  const float* mv  = (const float*)d_in[6];  // mem_values [1000,1024]
  const float* mp  = (const float*)d_in[7];  // mem_positions [1000]
  // d_in[8] = seq_len_q (unused; S fixed at 2048)
  (void)in_sizes; (void)n_in; (void)ws_size;

  float* ws = (float*)d_ws;  // needs B*1024*4 = 16 KB; harness ws is larger

  fused_stage1<<<NSIMS + NCOPYBLK, 256, 0, stream>>>(
      in0, q, k, v, mk, (float*)d_out, ws, (unsigned int)out_size);
  fused_stage2<<<B, 256, 0, stream>>>(
      am, mk, mv, mp, ws, (float*)d_out, (unsigned int)out_size);
}